// Round 17
// baseline (4636.585 us; speedup 1.0000x reference)
//
#include <hip/hip_runtime.h>

// ---------------------------------------------------------------------------
// LSTM scan, B=64 L=512 D=1024. Round 17 = R13 (replay-proven, 3.76ms) with
// ONE coupled change: fence-free consume.
//   - h fragment loads = RELAXED AGENT-scope atomic dword loads (bypass
//     L1/L2, read LLC directly -- same primitive the poll already proves).
//   - per-step acquire fence REMOVED (its only job was protecting plain h
//     loads from stale caches). Release side unchanged: plain h stores ->
//     syncthreads(vmcnt0) -> ACQ_REL RMW (wbL2 before arrival visible).
// Memory layout, grid(128), LDS(62KB), bar geometry (4 leaves x 8, 4096B),
// XPROJ_OFF: byte-identical to R13 (R14-R16 lesson: don't perturb these).
// ---------------------------------------------------------------------------

typedef float    f32x4 __attribute__((ext_vector_type(4)));
typedef _Float16 half8 __attribute__((ext_vector_type(8)));
typedef _Float16 half4 __attribute__((ext_vector_type(4)));
typedef unsigned int u32x4v __attribute__((ext_vector_type(4)));

#define AS1 __attribute__((address_space(1)))
#define AS3 __attribute__((address_space(3)))

#define B_  64
#define L_  512
#define D_  1024
#define N3_ 3072

// ws layout (bytes) -- identical to R13
#define WKT_OFF   0LL          // f16 [3072][1024]   6291456
#define WRT_OFF   6291456LL    // f16 [3072][1024]   6291456
#define XH_OFF    12582912LL   // f16 [B*L][1024]   67108864
#define H16_OFF   79691776LL   // f16 [2][64][1024]   262144
#define BAR_OFF   79953920LL   // unsigned[1024]        4096
#define XPROJ_OFF 79958016LL   // f16 [B*L][3072]   201326592

__device__ __forceinline__ float sigmoidf_fast(float x) {
  return __builtin_amdgcn_rcpf(1.f + __builtin_amdgcn_exp2f(-1.4426950408889634f * x));
}
__device__ __forceinline__ float tanhf_fast(float x) {
  return 1.f - 2.f * __builtin_amdgcn_rcpf(1.f + __builtin_amdgcn_exp2f(2.8853900817779268f * x));
}

// pinned (non-rematerializable) cached 16B load
#define ALOAD(dst, addr) \
  asm volatile("global_load_dwordx4 %0, %1, off" : "=v"(dst) : "v"(addr))
#define VMCNT0() asm volatile("s_waitcnt vmcnt(0)" ::: "memory")

__device__ __forceinline__ void gload_lds16(const void* g, void* l) {
  __builtin_amdgcn_global_load_lds((const AS1 unsigned int*)g,
                                   (AS3 unsigned int*)l, 16, 0, 0);
}

// ---------------- prep: zero the barrier space (kernel, replay-proven) -----
__global__ void zero_bar(unsigned* __restrict__ bar) {
  bar[blockIdx.x * 256 + threadIdx.x] = 0u;
}

// ---------------- prep: transpose + f32->f16 (Wk and Wr) -------------------
__global__ __launch_bounds__(256) void transpose_f16(
    const float* __restrict__ Wk, const float* __restrict__ Wr,
    _Float16* __restrict__ WkT, _Float16* __restrict__ WrT)
{
  __shared__ float tile[32][33];
  int b = blockIdx.x;
  const float* in = Wk; _Float16* outp = WkT;
  if (b >= 3072) { b -= 3072; in = Wr; outp = WrT; }
  const int n0 = (b % 96) * 32;
  const int k0 = (b / 96) * 32;
  const int tx = threadIdx.x & 31, ty = threadIdx.x >> 5;
#pragma unroll
  for (int i = 0; i < 32; i += 8)
    tile[ty + i][tx] = in[(size_t)(k0 + ty + i) * N3_ + n0 + tx];
  __syncthreads();
#pragma unroll
  for (int i = 0; i < 32; i += 8)
    outp[(size_t)(n0 + ty + i) * D_ + k0 + tx] = (_Float16)tile[tx][ty + i];
}

// ---------------- prep: x -> f16, h0 -> BOTH h16 buffers -------------------
__global__ void convert_inputs(const f32x4* __restrict__ x, const f32x4* __restrict__ h0,
                               half4* __restrict__ xh, half4* __restrict__ h16a,
                               half4* __restrict__ h16b)
{
  const int NX = (B_ * L_ * D_) / 4;
  const int NH = (B_ * D_) / 4;
  for (int i = blockIdx.x * blockDim.x + threadIdx.x; i < NX + NH;
       i += gridDim.x * blockDim.x) {
    if (i < NX) {
      xh[i] = __builtin_convertvector(x[i], half4);
    } else {
      half4 v = __builtin_convertvector(h0[i - NX], half4);
      h16a[i - NX] = v;
      h16b[i - NX] = v;
    }
  }
}

// ---------------- xproj GEMM (R7-fixed swizzle, replay-proven) -------------
__global__ __launch_bounds__(256) void gemm_xproj(
    const _Float16* __restrict__ A,    // [32768][1024]
    const _Float16* __restrict__ BT,   // [3072][1024]
    _Float16* __restrict__ C)          // [32768][3072] f16
{
  __shared__ _Float16 As[128 * 32];
  __shared__ _Float16 Bs[128 * 32];
  const int tid = threadIdx.x, wave = tid >> 6, lane = tid & 63;
  const int mt = blockIdx.x / 24, ntile = blockIdx.x % 24;
  const int m0 = mt * 128, n0 = ntile * 128;
  const int l15 = lane & 15, l4h = lane >> 4;
  const int wm = (wave >> 1) * 64, wn = (wave & 1) * 64;

  const int c0i = wave * 2;
  const int lrow = lane >> 2;                       // 0..15 within chunk
  const int skel = 8 * ((lane & 3) ^ (lrow & 3));   // 2-bit XOR, in-bounds

  f32x4 acc[4][4];
#pragma unroll
  for (int i = 0; i < 4; ++i)
#pragma unroll
    for (int j = 0; j < 4; ++j) { f32x4 z = {0.f,0.f,0.f,0.f}; acc[i][j] = z; }

  for (int kk = 0; kk < 32; ++kk) {
    __syncthreads();
#pragma unroll
    for (int i = 0; i < 2; ++i) {
      const int c = c0i + i;
      const int row = c * 16 + lrow;
      gload_lds16(A  + (((size_t)(m0 + row)) << 10) + (kk << 5) + skel, &As[c << 9]);
      gload_lds16(BT + (((size_t)(n0 + row)) << 10) + (kk << 5) + skel, &Bs[c << 9]);
    }
    __syncthreads();
    half8 af[4], bf[4];
#pragma unroll
    for (int i = 0; i < 4; ++i) {
      const int ar = wm + i * 16 + l15;
      af[i] = *(const half8*)&As[(ar << 5) + ((l4h ^ (ar & 3)) << 3)];
      const int br = wn + i * 16 + l15;
      bf[i] = *(const half8*)&Bs[(br << 5) + ((l4h ^ (br & 3)) << 3)];
    }
#pragma unroll
    for (int i = 0; i < 4; ++i)
#pragma unroll
      for (int j = 0; j < 4; ++j)
        acc[i][j] = __builtin_amdgcn_mfma_f32_16x16x32_f16(af[i], bf[j], acc[i][j], 0, 0, 0);
  }
#pragma unroll
  for (int i = 0; i < 4; ++i) {
    const int row = m0 + wm + i * 16 + l4h * 4;
#pragma unroll
    for (int j = 0; j < 4; ++j) {
      const int col = n0 + wn + j * 16 + l15;
      _Float16* cp = C + (size_t)row * N3_ + col;
#pragma unroll
      for (int r = 0; r < 4; ++r)
        __builtin_nontemporal_store((_Float16)acc[i][j][r], cp + (size_t)r * N3_);
    }
  }
}

// ---------------- persistent scan ------------------------------------------
// 128 WGs = 4 groups (b-tiles) x 32 d-slices (32 cols each); 4 waves own
// K-slices of 256. Barrier per group: 4 leaf counters (64B apart), 8 WGs
// each (R13 geometry). Arrive: ACQ_REL RMW own leaf (release = wbL2).
// Wait: relaxed poll of 4 leaves; NO acquire fence -- h is read via
// agent-scope relaxed atomic loads that bypass L1/L2 (same primitive as
// the poll itself, HW-proven by R12/R13).
__global__ __launch_bounds__(256, 1) void lstm_scan(
    const _Float16* __restrict__ WrT,   // [3072][1024]
    const _Float16* __restrict__ xproj, // [B*L][3072]
    const float*    __restrict__ c0,    // [64][1024]
    float*          __restrict__ out,   // [64][512][1024]
    _Float16*       __restrict__ h16,   // [2][64][1024]
    unsigned*       __restrict__ bar)
{
  const int tid = threadIdx.x, wave = tid >> 6, lane = tid & 63;
  const int bid = blockIdx.x;
  const int grp = bid & 3;           // b-tile group (independent scan)
  const int ord = bid >> 2;          // d-slice 0..31
  const int b0 = grp * 16;
  const int d0 = ord * 32;
  const int l15 = lane & 15, l4h = lane >> 4;
  const int kbase = wave * 256;

  unsigned* const gbase = bar + grp * 256;
  unsigned* const leafp = gbase + (ord & 3) * 16;   // own leaf line (8 WGs)

  // ---- stationary Wr fragments: 2 col-blocks x 3 gates x 8 kt ----
  half8 Wrf[2][3][8];
#pragma unroll
  for (int nt = 0; nt < 2; ++nt)
#pragma unroll
    for (int g = 0; g < 3; ++g) {
      const _Float16* rr = WrT + (size_t)(g * D_ + d0 + nt * 16 + l15) * D_ + kbase + l4h * 8;
#pragma unroll
      for (int kt = 0; kt < 8; ++kt) ALOAD(Wrf[nt][g][kt], rr + kt * 32);
    }
  VMCNT0();

  const int rb = tid >> 4;     // batch within tile
  const int rd16 = tid & 15;   // col within 16-block
  float c_0 = c0[(size_t)(b0 + rb) * D_ + d0 + rd16];
  float c_1 = c0[(size_t)(b0 + rb) * D_ + d0 + 16 + rd16];

  __shared__ float part[4][2][48][20];
  __shared__ float obuf[16][512];

  const size_t hoff    = (size_t)(b0 + l15) * D_ + kbase + l4h * 8;
  const size_t outidx0 = ((size_t)(b0 + rb) * L_) * D_ + d0 + rd16;
  const size_t hidx0   = (size_t)(b0 + rb) * D_ + d0 + rd16;
  const _Float16* xpbase = xproj + ((size_t)(b0 + rb) * L_) * N3_ + d0 + rd16;

  _Float16* hc = h16;            // h_t (both buffers pre-initialized with h0)
  _Float16* hn = h16 + B_ * D_;  // h_{t+1}

  // prologue: xp for t=0 (cold one-time reads)
  float xf0 = (float)xpbase[0],  xo0 = (float)xpbase[D_],      xg0 = (float)xpbase[2 * D_];
  float xf1 = (float)xpbase[16], xo1 = (float)xpbase[D_ + 16], xg1 = (float)xpbase[2 * D_ + 16];

  for (int t = 0; t < L_; ++t) {
    // ---- h fragments via agent-scope relaxed atomic dword loads (LLC) ----
    half8 af[8];
    const unsigned* hrow32 = (const unsigned*)(hc + hoff);
#pragma unroll
    for (int kt = 0; kt < 8; ++kt) {
      u32x4v u;
#pragma unroll
      for (int j = 0; j < 4; ++j)
        u[j] = __hip_atomic_load(hrow32 + kt * 16 + j, __ATOMIC_RELAXED,
                                 __HIP_MEMORY_SCOPE_AGENT);
      af[kt] = __builtin_bit_cast(half8, u);
    }

    f32x4 acc[2][3];
#pragma unroll
    for (int nt = 0; nt < 2; ++nt)
#pragma unroll
      for (int g = 0; g < 3; ++g) { f32x4 z = {0.f,0.f,0.f,0.f}; acc[nt][g] = z; }
#pragma unroll
    for (int kt = 0; kt < 8; ++kt)
#pragma unroll
      for (int nt = 0; nt < 2; ++nt)
#pragma unroll
        for (int g = 0; g < 3; ++g)
          acc[nt][g] = __builtin_amdgcn_mfma_f32_16x16x32_f16(af[kt], Wrf[nt][g][kt], acc[nt][g], 0, 0, 0);

    // ---- cross-wave reduce via LDS ----
#pragma unroll
    for (int nt = 0; nt < 2; ++nt)
#pragma unroll
      for (int g = 0; g < 3; ++g)
        *(f32x4*)&part[wave][nt][g * 16 + l15][l4h * 4] = acc[nt][g];
    __syncthreads();

    float fv0 = xf0, ov0 = xo0, gv0 = xg0;
    float fv1 = xf1, ov1 = xo1, gv1 = xg1;
#pragma unroll
    for (int w = 0; w < 4; ++w) {
      fv0 += part[w][0][rd16][rb];       fv1 += part[w][1][rd16][rb];
      ov0 += part[w][0][16 + rd16][rb];  ov1 += part[w][1][16 + rd16][rb];
      gv0 += part[w][0][32 + rd16][rb];  gv1 += part[w][1][32 + rd16][rb];
    }
    const float sf0 = sigmoidf_fast(fv0), sf1 = sigmoidf_fast(fv1);
    c_0 = c_0 * sf0 + (1.f - sf0) * tanhf_fast(gv0);
    c_1 = c_1 * sf1 + (1.f - sf1) * tanhf_fast(gv1);
    const float h0v = sigmoidf_fast(ov0) * tanhf_fast(c_0);
    const float h1v = sigmoidf_fast(ov1) * tanhf_fast(c_1);

    hn[hidx0]      = (_Float16)h0v;   // plain stores; released by arrive RMW
    hn[hidx0 + 16] = (_Float16)h1v;
    obuf[t & 15][tid]       = h0v;
    obuf[t & 15][tid + 256] = h1v;

    // ---- arrive: ONE ACQ_REL RMW on own leaf (release = wbL2; R13) ----
    __syncthreads();   // implicit vmcnt(0): h stores retired
    if (tid == 0)
      __hip_atomic_fetch_add(leafp, 1u, __ATOMIC_ACQ_REL, __HIP_MEMORY_SCOPE_AGENT);

    // ---- barrier shadow: out dump (every 16 steps) + xp[t+1] prefetch ----
    if ((t & 15) == 15) {
      float* op0 = out + outidx0 + (size_t)(t - 15) * D_;
#pragma unroll
      for (int j = 0; j < 16; ++j) {
        __builtin_nontemporal_store(obuf[j][tid],       op0 + (size_t)j * D_);
        __builtin_nontemporal_store(obuf[j][tid + 256], op0 + (size_t)j * D_ + 16);
      }
    }
    if (t + 1 < L_) {   // constant data: safe to read any time
      const _Float16* xp = xpbase + (size_t)(t + 1) * N3_;
      xf0 = (float)xp[0];   xo0 = (float)xp[D_];        xg0 = (float)xp[2 * D_];
      xf1 = (float)xp[16];  xo1 = (float)xp[D_ + 16];   xg1 = (float)xp[2 * D_ + 16];
    }
    __builtin_amdgcn_sched_barrier(0);   // keep shadow work before the wait

    // ---- wait: relaxed poll of 4 leaves; NO fence (h reads are LLC) ----
    if (tid == 0) {
      const unsigned tgt = 8u * (unsigned)(t + 1);
      while (true) {
        bool ok = true;
#pragma unroll
        for (int i = 0; i < 4; ++i)
          ok = ok & (__hip_atomic_load(gbase + i * 16, __ATOMIC_RELAXED,
                                       __HIP_MEMORY_SCOPE_AGENT) >= tgt);
        if (ok) break;
        __builtin_amdgcn_s_sleep(1);
      }
    }
    __syncthreads();

    _Float16* tmp = hc; hc = hn; hn = tmp;
  }
}

// ---------------------------------------------------------------------------
extern "C" void kernel_launch(void* const* d_in, const int* in_sizes, int n_in,
                              void* d_out, int out_size, void* d_ws, size_t ws_size,
                              hipStream_t stream) {
  const float* x  = (const float*)d_in[0];
  const float* Wk = (const float*)d_in[1];
  const float* Wr = (const float*)d_in[2];
  const float* c0 = (const float*)d_in[3];
  const float* h0 = (const float*)d_in[4];
  float* out = (float*)d_out;

  char* ws = (char*)d_ws;
  _Float16* WkT   = (_Float16*)(ws + WKT_OFF);
  _Float16* WrT   = (_Float16*)(ws + WRT_OFF);
  _Float16* xh    = (_Float16*)(ws + XH_OFF);
  _Float16* h16   = (_Float16*)(ws + H16_OFF);
  unsigned* bar   = (unsigned*)(ws + BAR_OFF);
  _Float16* xproj = (_Float16*)(ws + XPROJ_OFF);

  hipLaunchKernelGGL(zero_bar, dim3(4), dim3(256), 0, stream, bar);
  hipLaunchKernelGGL(transpose_f16, dim3(6144), dim3(256), 0, stream,
                     Wk, Wr, WkT, WrT);
  hipLaunchKernelGGL(convert_inputs, dim3(2048), dim3(256), 0, stream,
                     (const f32x4*)x, (const f32x4*)h0,
                     (half4*)xh, (half4*)h16, (half4*)(h16 + B_ * D_));
  hipLaunchKernelGGL(gemm_xproj, dim3(6144), dim3(256), 0, stream,
                     xh, WkT, xproj);

  void* kargs[6] = {(void*)&WrT, (void*)&xproj, (void*)&c0,
                    (void*)&out, (void*)&h16, (void*)&bar};
  hipLaunchCooperativeKernel((void*)lstm_scan, dim3(128), dim3(256), kargs, 0, stream);
}

// Round 18
// 3664.291 us; speedup vs baseline: 1.2653x; 1.2653x over previous
//
#include <hip/hip_runtime.h>

// ---------------------------------------------------------------------------
// LSTM scan, B=64 L=512 D=1024. Round 18 = fan-in 16 done with R13's proven
// per-thread register load:
//   64 WGs = 4 groups x 16; WG = 16 batches x 64 cols, 512 THREADS (8 waves).
//   Wave (ks=w&3, ch=w>>2): K-slice 256, col-half 32 -> Wrf[2][3][8] = 192
//   regs/thread (R13-proven; R14/15's 384-reg geometry was the launch-fail).
//   __launch_bounds__(512,2) caps at 256 regs/wave.
//   LDS: part[4][4][48][20] = 61440B. obuf dropped; out = NT stores in shadow.
// Protocol byte-identical to R13: zero_bar kernel, 4 leaf lines (depth 4),
// ACQ_REL arrive, relaxed poll + ONE agent acquire fence, plain h loads
// (R17 measured: fence+vector gather beats fence-free+atomic gather).
// ---------------------------------------------------------------------------

typedef float    f32x4 __attribute__((ext_vector_type(4)));
typedef _Float16 half8 __attribute__((ext_vector_type(8)));
typedef _Float16 half4 __attribute__((ext_vector_type(4)));

#define AS1 __attribute__((address_space(1)))
#define AS3 __attribute__((address_space(3)))

#define B_  64
#define L_  512
#define D_  1024
#define N3_ 3072

// ws layout (bytes) -- identical to R13
#define WKT_OFF   0LL          // f16 [3072][1024]   6291456
#define WRT_OFF   6291456LL    // f16 [3072][1024]   6291456
#define XH_OFF    12582912LL   // f16 [B*L][1024]   67108864
#define H16_OFF   79691776LL   // f16 [2][64][1024]   262144
#define BAR_OFF   79953920LL   // unsigned[1024]        4096
#define XPROJ_OFF 79958016LL   // f16 [B*L][3072]   201326592

__device__ __forceinline__ float sigmoidf_fast(float x) {
  return __builtin_amdgcn_rcpf(1.f + __builtin_amdgcn_exp2f(-1.4426950408889634f * x));
}
__device__ __forceinline__ float tanhf_fast(float x) {
  return 1.f - 2.f * __builtin_amdgcn_rcpf(1.f + __builtin_amdgcn_exp2f(2.8853900817779268f * x));
}

// pinned (non-rematerializable) cached 16B load
#define ALOAD(dst, addr) \
  asm volatile("global_load_dwordx4 %0, %1, off" : "=v"(dst) : "v"(addr))
#define VMCNT0() asm volatile("s_waitcnt vmcnt(0)" ::: "memory")

__device__ __forceinline__ void gload_lds16(const void* g, void* l) {
  __builtin_amdgcn_global_load_lds((const AS1 unsigned int*)g,
                                   (AS3 unsigned int*)l, 16, 0, 0);
}

// ---------------- prep: zero the barrier space (kernel, replay-proven) -----
__global__ void zero_bar(unsigned* __restrict__ bar) {
  bar[blockIdx.x * 256 + threadIdx.x] = 0u;
}

// ---------------- prep: transpose + f32->f16 (Wk and Wr) -------------------
__global__ __launch_bounds__(256) void transpose_f16(
    const float* __restrict__ Wk, const float* __restrict__ Wr,
    _Float16* __restrict__ WkT, _Float16* __restrict__ WrT)
{
  __shared__ float tile[32][33];
  int b = blockIdx.x;
  const float* in = Wk; _Float16* outp = WkT;
  if (b >= 3072) { b -= 3072; in = Wr; outp = WrT; }
  const int n0 = (b % 96) * 32;
  const int k0 = (b / 96) * 32;
  const int tx = threadIdx.x & 31, ty = threadIdx.x >> 5;
#pragma unroll
  for (int i = 0; i < 32; i += 8)
    tile[ty + i][tx] = in[(size_t)(k0 + ty + i) * N3_ + n0 + tx];
  __syncthreads();
#pragma unroll
  for (int i = 0; i < 32; i += 8)
    outp[(size_t)(n0 + ty + i) * D_ + k0 + tx] = (_Float16)tile[tx][ty + i];
}

// ---------------- prep: x -> f16, h0 -> BOTH h16 buffers -------------------
__global__ void convert_inputs(const f32x4* __restrict__ x, const f32x4* __restrict__ h0,
                               half4* __restrict__ xh, half4* __restrict__ h16a,
                               half4* __restrict__ h16b)
{
  const int NX = (B_ * L_ * D_) / 4;
  const int NH = (B_ * D_) / 4;
  for (int i = blockIdx.x * blockDim.x + threadIdx.x; i < NX + NH;
       i += gridDim.x * blockDim.x) {
    if (i < NX) {
      xh[i] = __builtin_convertvector(x[i], half4);
    } else {
      half4 v = __builtin_convertvector(h0[i - NX], half4);
      h16a[i - NX] = v;
      h16b[i - NX] = v;
    }
  }
}

// ---------------- xproj GEMM (R7-fixed swizzle, replay-proven) -------------
__global__ __launch_bounds__(256) void gemm_xproj(
    const _Float16* __restrict__ A,    // [32768][1024]
    const _Float16* __restrict__ BT,   // [3072][1024]
    _Float16* __restrict__ C)          // [32768][3072] f16
{
  __shared__ _Float16 As[128 * 32];
  __shared__ _Float16 Bs[128 * 32];
  const int tid = threadIdx.x, wave = tid >> 6, lane = tid & 63;
  const int mt = blockIdx.x / 24, ntile = blockIdx.x % 24;
  const int m0 = mt * 128, n0 = ntile * 128;
  const int l15 = lane & 15, l4h = lane >> 4;
  const int wm = (wave >> 1) * 64, wn = (wave & 1) * 64;

  const int c0i = wave * 2;
  const int lrow = lane >> 2;                       // 0..15 within chunk
  const int skel = 8 * ((lane & 3) ^ (lrow & 3));   // 2-bit XOR, in-bounds

  f32x4 acc[4][4];
#pragma unroll
  for (int i = 0; i < 4; ++i)
#pragma unroll
    for (int j = 0; j < 4; ++j) { f32x4 z = {0.f,0.f,0.f,0.f}; acc[i][j] = z; }

  for (int kk = 0; kk < 32; ++kk) {
    __syncthreads();
#pragma unroll
    for (int i = 0; i < 2; ++i) {
      const int c = c0i + i;
      const int row = c * 16 + lrow;
      gload_lds16(A  + (((size_t)(m0 + row)) << 10) + (kk << 5) + skel, &As[c << 9]);
      gload_lds16(BT + (((size_t)(n0 + row)) << 10) + (kk << 5) + skel, &Bs[c << 9]);
    }
    __syncthreads();
    half8 af[4], bf[4];
#pragma unroll
    for (int i = 0; i < 4; ++i) {
      const int ar = wm + i * 16 + l15;
      af[i] = *(const half8*)&As[(ar << 5) + ((l4h ^ (ar & 3)) << 3)];
      const int br = wn + i * 16 + l15;
      bf[i] = *(const half8*)&Bs[(br << 5) + ((l4h ^ (br & 3)) << 3)];
    }
#pragma unroll
    for (int i = 0; i < 4; ++i)
#pragma unroll
      for (int j = 0; j < 4; ++j)
        acc[i][j] = __builtin_amdgcn_mfma_f32_16x16x32_f16(af[i], bf[j], acc[i][j], 0, 0, 0);
  }
#pragma unroll
  for (int i = 0; i < 4; ++i) {
    const int row = m0 + wm + i * 16 + l4h * 4;
#pragma unroll
    for (int j = 0; j < 4; ++j) {
      const int col = n0 + wn + j * 16 + l15;
      _Float16* cp = C + (size_t)row * N3_ + col;
#pragma unroll
      for (int r = 0; r < 4; ++r)
        __builtin_nontemporal_store((_Float16)acc[i][j][r], cp + (size_t)r * N3_);
    }
  }
}

// ---------------- persistent scan ------------------------------------------
// 64 WGs = 4 groups x 16 d-slices (64 cols); 512 threads = 8 waves.
// Wave w: ks = w&3 (K-slice 256), ch = w>>2 (32-col half -> 2 nt blocks).
// Barrier per group: 4 leaf lines (64B apart), 4 WGs each (R13 layout).
__global__ __launch_bounds__(512, 2) void lstm_scan(
    const _Float16* __restrict__ WrT,   // [3072][1024]
    const _Float16* __restrict__ xproj, // [B*L][3072]
    const float*    __restrict__ c0,    // [64][1024]
    float*          __restrict__ out,   // [64][512][1024]
    _Float16*       __restrict__ h16,   // [2][64][1024]
    unsigned*       __restrict__ bar)
{
  const int tid = threadIdx.x, wave = tid >> 6, lane = tid & 63;
  const int bid = blockIdx.x;
  const int grp = bid & 3;           // b-tile group (independent scan)
  const int ord = bid >> 2;          // d-slice 0..15
  const int b0 = grp * 16;
  const int d0 = ord * 64;
  const int l15 = lane & 15, l4h = lane >> 4;
  const int ks = wave & 3, ch = wave >> 2;
  const int kbase = ks * 256;

  unsigned* const gbase = bar + grp * 256;
  unsigned* const leafp = gbase + (ord & 3) * 16;   // own leaf line (4 WGs)

  // ---- stationary Wr fragments: 2 nt blocks x 3 gates x 8 kt = 192 regs ----
  half8 Wrf[2][3][8];
#pragma unroll
  for (int nt = 0; nt < 2; ++nt)
#pragma unroll
    for (int g = 0; g < 3; ++g) {
      const _Float16* rr = WrT +
          (size_t)(g * D_ + d0 + ch * 32 + nt * 16 + l15) * D_ + kbase + l4h * 8;
#pragma unroll
      for (int kt = 0; kt < 8; ++kt) ALOAD(Wrf[nt][g][kt], rr + kt * 32);
    }
  VMCNT0();

  // final-reduce mapping: thread -> (rb, c) with two col-halves H=0,1
  const int rb = tid >> 5;       // batch 0..15
  const int c  = tid & 31;       // col within half
  const int ntc = c >> 4, rd16 = c & 15;
  float cc[2];
  cc[0] = c0[(size_t)(b0 + rb) * D_ + d0 + c];
  cc[1] = c0[(size_t)(b0 + rb) * D_ + d0 + 32 + c];

  __shared__ float part[4][4][48][20];   // [ks][2*ch+nt][g*16+l15][l4h*4+r]

  const size_t hoff    = (size_t)(b0 + l15) * D_ + kbase + l4h * 8;
  const size_t outidx0 = ((size_t)(b0 + rb) * L_) * D_ + d0 + c;
  const size_t hidx0   = (size_t)(b0 + rb) * D_ + d0 + c;
  const _Float16* xpbase = xproj + ((size_t)(b0 + rb) * L_) * N3_ + d0 + c;

  _Float16* hc = h16;            // h_t (both buffers pre-initialized with h0)
  _Float16* hn = h16 + B_ * D_;  // h_{t+1}

  // prologue: xp for t=0 (cold one-time reads): [gate][H]
  float xpv[3][2];
#pragma unroll
  for (int g = 0; g < 3; ++g) {
    xpv[g][0] = (float)xpbase[(size_t)g * D_];
    xpv[g][1] = (float)xpbase[(size_t)g * D_ + 32];
  }

  for (int t = 0; t < L_; ++t) {
    // ---- h fragments (plain vector loads; fresh due to last acquire) ----
    half8 af[8];
    const _Float16* hrow = hc + hoff;
#pragma unroll
    for (int kt = 0; kt < 8; ++kt) af[kt] = *(const half8*)(hrow + kt * 32);

    f32x4 acc[2][3];
#pragma unroll
    for (int nt = 0; nt < 2; ++nt)
#pragma unroll
      for (int g = 0; g < 3; ++g) { f32x4 z = {0.f,0.f,0.f,0.f}; acc[nt][g] = z; }
#pragma unroll
    for (int kt = 0; kt < 8; ++kt)
#pragma unroll
      for (int nt = 0; nt < 2; ++nt)
#pragma unroll
        for (int g = 0; g < 3; ++g)
          acc[nt][g] = __builtin_amdgcn_mfma_f32_16x16x32_f16(af[kt], Wrf[nt][g][kt], acc[nt][g], 0, 0, 0);

    // ---- cross-wave reduce via LDS ----
#pragma unroll
    for (int nt = 0; nt < 2; ++nt)
#pragma unroll
      for (int g = 0; g < 3; ++g)
        *(f32x4*)&part[ks][ch * 2 + nt][g * 16 + l15][l4h * 4] = acc[nt][g];
    __syncthreads();

    float hv[2];
#pragma unroll
    for (int H = 0; H < 2; ++H) {
      const int e = H * 2 + ntc;
      float fv = xpv[0][H], ov = xpv[1][H], gv = xpv[2][H];
#pragma unroll
      for (int k = 0; k < 4; ++k) {
        fv += part[k][e][rd16][rb];
        ov += part[k][e][16 + rd16][rb];
        gv += part[k][e][32 + rd16][rb];
      }
      const float sf = sigmoidf_fast(fv);
      cc[H] = cc[H] * sf + (1.f - sf) * tanhf_fast(gv);
      hv[H] = sigmoidf_fast(ov) * tanhf_fast(cc[H]);
    }

    hn[hidx0]      = (_Float16)hv[0];   // plain cached stores (R10: NT hurts)
    hn[hidx0 + 32] = (_Float16)hv[1];

    // ---- arrive: ONE ACQ_REL RMW on own leaf (release = wbL2; R13) ----
    __syncthreads();   // implicit vmcnt(0): h stores retired
    if (tid == 0)
      __hip_atomic_fetch_add(leafp, 1u, __ATOMIC_ACQ_REL, __HIP_MEMORY_SCOPE_AGENT);

    // ---- barrier shadow: NT out stores + xp[t+1] prefetch ----
    {
      float* op = out + outidx0 + (size_t)t * D_;
      __builtin_nontemporal_store(hv[0], op);
      __builtin_nontemporal_store(hv[1], op + 32);
    }
    if (t + 1 < L_) {   // constant data: correct to read pre-fence
      const _Float16* xp = xpbase + (size_t)(t + 1) * N3_;
#pragma unroll
      for (int g = 0; g < 3; ++g) {
        xpv[g][0] = (float)xp[(size_t)g * D_];
        xpv[g][1] = (float)xp[(size_t)g * D_ + 32];
      }
    }
    __builtin_amdgcn_sched_barrier(0);   // keep shadow work before the wait

    // ---- wait: poll 4 leaves >= 4*(t+1) + ONE agent acquire fence ----
    if (tid == 0) {
      const unsigned tgt = 4u * (unsigned)(t + 1);
      while (true) {
        bool ok = true;
#pragma unroll
        for (int i = 0; i < 4; ++i)
          ok = ok & (__hip_atomic_load(gbase + i * 16, __ATOMIC_RELAXED,
                                       __HIP_MEMORY_SCOPE_AGENT) >= tgt);
        if (ok) break;
        __builtin_amdgcn_s_sleep(1);
      }
      __builtin_amdgcn_fence(__ATOMIC_ACQUIRE, "agent");
    }
    __syncthreads();

    _Float16* tmp = hc; hc = hn; hn = tmp;
  }
}

// ---------------------------------------------------------------------------
extern "C" void kernel_launch(void* const* d_in, const int* in_sizes, int n_in,
                              void* d_out, int out_size, void* d_ws, size_t ws_size,
                              hipStream_t stream) {
  const float* x  = (const float*)d_in[0];
  const float* Wk = (const float*)d_in[1];
  const float* Wr = (const float*)d_in[2];
  const float* c0 = (const float*)d_in[3];
  const float* h0 = (const float*)d_in[4];
  float* out = (float*)d_out;

  char* ws = (char*)d_ws;
  _Float16* WkT   = (_Float16*)(ws + WKT_OFF);
  _Float16* WrT   = (_Float16*)(ws + WRT_OFF);
  _Float16* xh    = (_Float16*)(ws + XH_OFF);
  _Float16* h16   = (_Float16*)(ws + H16_OFF);
  unsigned* bar   = (unsigned*)(ws + BAR_OFF);
  _Float16* xproj = (_Float16*)(ws + XPROJ_OFF);

  hipLaunchKernelGGL(zero_bar, dim3(4), dim3(256), 0, stream, bar);
  hipLaunchKernelGGL(transpose_f16, dim3(6144), dim3(256), 0, stream,
                     Wk, Wr, WkT, WrT);
  hipLaunchKernelGGL(convert_inputs, dim3(2048), dim3(256), 0, stream,
                     (const f32x4*)x, (const f32x4*)h0,
                     (half4*)xh, (half4*)h16, (half4*)(h16 + B_ * D_));
  hipLaunchKernelGGL(gemm_xproj, dim3(6144), dim3(256), 0, stream,
                     xh, WkT, xproj);

  void* kargs[6] = {(void*)&WrT, (void*)&xproj, (void*)&c0,
                    (void*)&out, (void*)&h16, (void*)&bar};
  hipLaunchCooperativeKernel((void*)lstm_scan, dim3(64), dim3(512), kargs, 0, stream);
}

// Round 19
// 3578.474 us; speedup vs baseline: 1.2957x; 1.0240x over previous
//
#include <hip/hip_runtime.h>

// ---------------------------------------------------------------------------
// LSTM scan, B=64 L=512 D=1024. Round 19 = R18 (passed, 3.66ms) with ONE
// change: part pad 20 -> 21.
//   R18's 512-thr reduce read had 4-way LDS bank conflicts (e-stride
//   48*20=960 ≡ 0 mod 32 banks aliased lane groups; SQ_LDS_BANK_CONFLICT
//   tripled vs R13). Stride 21: 21*rd16 covers 16 distinct banks and
//   e-stride 1008 ≡ 16 mod 32 -> disjoint halves -> exact 2-way (free).
//   part[4][4][48][21] = 64512B <= 64KB static cap.
// Everything else byte-identical to R18 (geometry 64 WGs x 512thr, R13
// protocol: 4 leaf lines, ACQ_REL arrive, relaxed poll + one agent acquire
// fence, plain vector h loads, shadow NT out + xp prefetch, xproj GEMM).
// ---------------------------------------------------------------------------

typedef float    f32x4 __attribute__((ext_vector_type(4)));
typedef _Float16 half8 __attribute__((ext_vector_type(8)));
typedef _Float16 half4 __attribute__((ext_vector_type(4)));

#define AS1 __attribute__((address_space(1)))
#define AS3 __attribute__((address_space(3)))

#define B_  64
#define L_  512
#define D_  1024
#define N3_ 3072

// ws layout (bytes) -- identical to R13/R18
#define WKT_OFF   0LL          // f16 [3072][1024]   6291456
#define WRT_OFF   6291456LL    // f16 [3072][1024]   6291456
#define XH_OFF    12582912LL   // f16 [B*L][1024]   67108864
#define H16_OFF   79691776LL   // f16 [2][64][1024]   262144
#define BAR_OFF   79953920LL   // unsigned[1024]        4096
#define XPROJ_OFF 79958016LL   // f16 [B*L][3072]   201326592

__device__ __forceinline__ float sigmoidf_fast(float x) {
  return __builtin_amdgcn_rcpf(1.f + __builtin_amdgcn_exp2f(-1.4426950408889634f * x));
}
__device__ __forceinline__ float tanhf_fast(float x) {
  return 1.f - 2.f * __builtin_amdgcn_rcpf(1.f + __builtin_amdgcn_exp2f(2.8853900817779268f * x));
}

// pinned (non-rematerializable) cached 16B load
#define ALOAD(dst, addr) \
  asm volatile("global_load_dwordx4 %0, %1, off" : "=v"(dst) : "v"(addr))
#define VMCNT0() asm volatile("s_waitcnt vmcnt(0)" ::: "memory")

__device__ __forceinline__ void gload_lds16(const void* g, void* l) {
  __builtin_amdgcn_global_load_lds((const AS1 unsigned int*)g,
                                   (AS3 unsigned int*)l, 16, 0, 0);
}

// ---------------- prep: zero the barrier space (kernel, replay-proven) -----
__global__ void zero_bar(unsigned* __restrict__ bar) {
  bar[blockIdx.x * 256 + threadIdx.x] = 0u;
}

// ---------------- prep: transpose + f32->f16 (Wk and Wr) -------------------
__global__ __launch_bounds__(256) void transpose_f16(
    const float* __restrict__ Wk, const float* __restrict__ Wr,
    _Float16* __restrict__ WkT, _Float16* __restrict__ WrT)
{
  __shared__ float tile[32][33];
  int b = blockIdx.x;
  const float* in = Wk; _Float16* outp = WkT;
  if (b >= 3072) { b -= 3072; in = Wr; outp = WrT; }
  const int n0 = (b % 96) * 32;
  const int k0 = (b / 96) * 32;
  const int tx = threadIdx.x & 31, ty = threadIdx.x >> 5;
#pragma unroll
  for (int i = 0; i < 32; i += 8)
    tile[ty + i][tx] = in[(size_t)(k0 + ty + i) * N3_ + n0 + tx];
  __syncthreads();
#pragma unroll
  for (int i = 0; i < 32; i += 8)
    outp[(size_t)(n0 + ty + i) * D_ + k0 + tx] = (_Float16)tile[tx][ty + i];
}

// ---------------- prep: x -> f16, h0 -> BOTH h16 buffers -------------------
__global__ void convert_inputs(const f32x4* __restrict__ x, const f32x4* __restrict__ h0,
                               half4* __restrict__ xh, half4* __restrict__ h16a,
                               half4* __restrict__ h16b)
{
  const int NX = (B_ * L_ * D_) / 4;
  const int NH = (B_ * D_) / 4;
  for (int i = blockIdx.x * blockDim.x + threadIdx.x; i < NX + NH;
       i += gridDim.x * blockDim.x) {
    if (i < NX) {
      xh[i] = __builtin_convertvector(x[i], half4);
    } else {
      half4 v = __builtin_convertvector(h0[i - NX], half4);
      h16a[i - NX] = v;
      h16b[i - NX] = v;
    }
  }
}

// ---------------- xproj GEMM (R7-fixed swizzle, replay-proven) -------------
__global__ __launch_bounds__(256) void gemm_xproj(
    const _Float16* __restrict__ A,    // [32768][1024]
    const _Float16* __restrict__ BT,   // [3072][1024]
    _Float16* __restrict__ C)          // [32768][3072] f16
{
  __shared__ _Float16 As[128 * 32];
  __shared__ _Float16 Bs[128 * 32];
  const int tid = threadIdx.x, wave = tid >> 6, lane = tid & 63;
  const int mt = blockIdx.x / 24, ntile = blockIdx.x % 24;
  const int m0 = mt * 128, n0 = ntile * 128;
  const int l15 = lane & 15, l4h = lane >> 4;
  const int wm = (wave >> 1) * 64, wn = (wave & 1) * 64;

  const int c0i = wave * 2;
  const int lrow = lane >> 2;                       // 0..15 within chunk
  const int skel = 8 * ((lane & 3) ^ (lrow & 3));   // 2-bit XOR, in-bounds

  f32x4 acc[4][4];
#pragma unroll
  for (int i = 0; i < 4; ++i)
#pragma unroll
    for (int j = 0; j < 4; ++j) { f32x4 z = {0.f,0.f,0.f,0.f}; acc[i][j] = z; }

  for (int kk = 0; kk < 32; ++kk) {
    __syncthreads();
#pragma unroll
    for (int i = 0; i < 2; ++i) {
      const int c = c0i + i;
      const int row = c * 16 + lrow;
      gload_lds16(A  + (((size_t)(m0 + row)) << 10) + (kk << 5) + skel, &As[c << 9]);
      gload_lds16(BT + (((size_t)(n0 + row)) << 10) + (kk << 5) + skel, &Bs[c << 9]);
    }
    __syncthreads();
    half8 af[4], bf[4];
#pragma unroll
    for (int i = 0; i < 4; ++i) {
      const int ar = wm + i * 16 + l15;
      af[i] = *(const half8*)&As[(ar << 5) + ((l4h ^ (ar & 3)) << 3)];
      const int br = wn + i * 16 + l15;
      bf[i] = *(const half8*)&Bs[(br << 5) + ((l4h ^ (br & 3)) << 3)];
    }
#pragma unroll
    for (int i = 0; i < 4; ++i)
#pragma unroll
      for (int j = 0; j < 4; ++j)
        acc[i][j] = __builtin_amdgcn_mfma_f32_16x16x32_f16(af[i], bf[j], acc[i][j], 0, 0, 0);
  }
#pragma unroll
  for (int i = 0; i < 4; ++i) {
    const int row = m0 + wm + i * 16 + l4h * 4;
#pragma unroll
    for (int j = 0; j < 4; ++j) {
      const int col = n0 + wn + j * 16 + l15;
      _Float16* cp = C + (size_t)row * N3_ + col;
#pragma unroll
      for (int r = 0; r < 4; ++r)
        __builtin_nontemporal_store((_Float16)acc[i][j][r], cp + (size_t)r * N3_);
    }
  }
}

// ---------------- persistent scan ------------------------------------------
// 64 WGs = 4 groups x 16 d-slices (64 cols); 512 threads = 8 waves.
// Wave w: ks = w&3 (K-slice 256), ch = w>>2 (32-col half -> 2 nt blocks).
// Barrier per group: 4 leaf lines (64B apart), 4 WGs each (R13 layout).
__global__ __launch_bounds__(512, 2) void lstm_scan(
    const _Float16* __restrict__ WrT,   // [3072][1024]
    const _Float16* __restrict__ xproj, // [B*L][3072]
    const float*    __restrict__ c0,    // [64][1024]
    float*          __restrict__ out,   // [64][512][1024]
    _Float16*       __restrict__ h16,   // [2][64][1024]
    unsigned*       __restrict__ bar)
{
  const int tid = threadIdx.x, wave = tid >> 6, lane = tid & 63;
  const int bid = blockIdx.x;
  const int grp = bid & 3;           // b-tile group (independent scan)
  const int ord = bid >> 2;          // d-slice 0..15
  const int b0 = grp * 16;
  const int d0 = ord * 64;
  const int l15 = lane & 15, l4h = lane >> 4;
  const int ks = wave & 3, ch = wave >> 2;
  const int kbase = ks * 256;

  unsigned* const gbase = bar + grp * 256;
  unsigned* const leafp = gbase + (ord & 3) * 16;   // own leaf line (4 WGs)

  // ---- stationary Wr fragments: 2 nt blocks x 3 gates x 8 kt = 192 regs ----
  half8 Wrf[2][3][8];
#pragma unroll
  for (int nt = 0; nt < 2; ++nt)
#pragma unroll
    for (int g = 0; g < 3; ++g) {
      const _Float16* rr = WrT +
          (size_t)(g * D_ + d0 + ch * 32 + nt * 16 + l15) * D_ + kbase + l4h * 8;
#pragma unroll
      for (int kt = 0; kt < 8; ++kt) ALOAD(Wrf[nt][g][kt], rr + kt * 32);
    }
  VMCNT0();

  // final-reduce mapping: thread -> (rb, c) with two col-halves H=0,1
  const int rb = tid >> 5;       // batch 0..15
  const int c  = tid & 31;       // col within half
  const int ntc = c >> 4, rd16 = c & 15;
  float cc[2];
  cc[0] = c0[(size_t)(b0 + rb) * D_ + d0 + c];
  cc[1] = c0[(size_t)(b0 + rb) * D_ + d0 + 32 + c];

  __shared__ float part[4][4][48][21];   // pad 21: 64512B, 2-way banks (free)

  const size_t hoff    = (size_t)(b0 + l15) * D_ + kbase + l4h * 8;
  const size_t outidx0 = ((size_t)(b0 + rb) * L_) * D_ + d0 + c;
  const size_t hidx0   = (size_t)(b0 + rb) * D_ + d0 + c;
  const _Float16* xpbase = xproj + ((size_t)(b0 + rb) * L_) * N3_ + d0 + c;

  _Float16* hc = h16;            // h_t (both buffers pre-initialized with h0)
  _Float16* hn = h16 + B_ * D_;  // h_{t+1}

  // prologue: xp for t=0 (cold one-time reads): [gate][H]
  float xpv[3][2];
#pragma unroll
  for (int g = 0; g < 3; ++g) {
    xpv[g][0] = (float)xpbase[(size_t)g * D_];
    xpv[g][1] = (float)xpbase[(size_t)g * D_ + 32];
  }

  for (int t = 0; t < L_; ++t) {
    // ---- h fragments (plain vector loads; fresh due to last acquire) ----
    half8 af[8];
    const _Float16* hrow = hc + hoff;
#pragma unroll
    for (int kt = 0; kt < 8; ++kt) af[kt] = *(const half8*)(hrow + kt * 32);

    f32x4 acc[2][3];
#pragma unroll
    for (int nt = 0; nt < 2; ++nt)
#pragma unroll
      for (int g = 0; g < 3; ++g) { f32x4 z = {0.f,0.f,0.f,0.f}; acc[nt][g] = z; }
#pragma unroll
    for (int kt = 0; kt < 8; ++kt)
#pragma unroll
      for (int nt = 0; nt < 2; ++nt)
#pragma unroll
        for (int g = 0; g < 3; ++g)
          acc[nt][g] = __builtin_amdgcn_mfma_f32_16x16x32_f16(af[kt], Wrf[nt][g][kt], acc[nt][g], 0, 0, 0);

    // ---- cross-wave reduce via LDS ----
#pragma unroll
    for (int nt = 0; nt < 2; ++nt)
#pragma unroll
      for (int g = 0; g < 3; ++g)
        *(f32x4*)&part[ks][ch * 2 + nt][g * 16 + l15][l4h * 4] = acc[nt][g];
    __syncthreads();

    float hv[2];
#pragma unroll
    for (int H = 0; H < 2; ++H) {
      const int e = H * 2 + ntc;
      float fv = xpv[0][H], ov = xpv[1][H], gv = xpv[2][H];
#pragma unroll
      for (int k = 0; k < 4; ++k) {
        fv += part[k][e][rd16][rb];
        ov += part[k][e][16 + rd16][rb];
        gv += part[k][e][32 + rd16][rb];
      }
      const float sf = sigmoidf_fast(fv);
      cc[H] = cc[H] * sf + (1.f - sf) * tanhf_fast(gv);
      hv[H] = sigmoidf_fast(ov) * tanhf_fast(cc[H]);
    }

    hn[hidx0]      = (_Float16)hv[0];   // plain cached stores (R10: NT hurts)
    hn[hidx0 + 32] = (_Float16)hv[1];

    // ---- arrive: ONE ACQ_REL RMW on own leaf (release = wbL2; R13) ----
    __syncthreads();   // implicit vmcnt(0): h stores retired
    if (tid == 0)
      __hip_atomic_fetch_add(leafp, 1u, __ATOMIC_ACQ_REL, __HIP_MEMORY_SCOPE_AGENT);

    // ---- barrier shadow: NT out stores + xp[t+1] prefetch ----
    {
      float* op = out + outidx0 + (size_t)t * D_;
      __builtin_nontemporal_store(hv[0], op);
      __builtin_nontemporal_store(hv[1], op + 32);
    }
    if (t + 1 < L_) {   // constant data: correct to read pre-fence
      const _Float16* xp = xpbase + (size_t)(t + 1) * N3_;
#pragma unroll
      for (int g = 0; g < 3; ++g) {
        xpv[g][0] = (float)xp[(size_t)g * D_];
        xpv[g][1] = (float)xp[(size_t)g * D_ + 32];
      }
    }
    __builtin_amdgcn_sched_barrier(0);   // keep shadow work before the wait

    // ---- wait: poll 4 leaves >= 4*(t+1) + ONE agent acquire fence ----
    if (tid == 0) {
      const unsigned tgt = 4u * (unsigned)(t + 1);
      while (true) {
        bool ok = true;
#pragma unroll
        for (int i = 0; i < 4; ++i)
          ok = ok & (__hip_atomic_load(gbase + i * 16, __ATOMIC_RELAXED,
                                       __HIP_MEMORY_SCOPE_AGENT) >= tgt);
        if (ok) break;
        __builtin_amdgcn_s_sleep(1);
      }
      __builtin_amdgcn_fence(__ATOMIC_ACQUIRE, "agent");
    }
    __syncthreads();

    _Float16* tmp = hc; hc = hn; hn = tmp;
  }
}

// ---------------------------------------------------------------------------
extern "C" void kernel_launch(void* const* d_in, const int* in_sizes, int n_in,
                              void* d_out, int out_size, void* d_ws, size_t ws_size,
                              hipStream_t stream) {
  const float* x  = (const float*)d_in[0];
  const float* Wk = (const float*)d_in[1];
  const float* Wr = (const float*)d_in[2];
  const float* c0 = (const float*)d_in[3];
  const float* h0 = (const float*)d_in[4];
  float* out = (float*)d_out;

  char* ws = (char*)d_ws;
  _Float16* WkT   = (_Float16*)(ws + WKT_OFF);
  _Float16* WrT   = (_Float16*)(ws + WRT_OFF);
  _Float16* xh    = (_Float16*)(ws + XH_OFF);
  _Float16* h16   = (_Float16*)(ws + H16_OFF);
  unsigned* bar   = (unsigned*)(ws + BAR_OFF);
  _Float16* xproj = (_Float16*)(ws + XPROJ_OFF);

  hipLaunchKernelGGL(zero_bar, dim3(4), dim3(256), 0, stream, bar);
  hipLaunchKernelGGL(transpose_f16, dim3(6144), dim3(256), 0, stream,
                     Wk, Wr, WkT, WrT);
  hipLaunchKernelGGL(convert_inputs, dim3(2048), dim3(256), 0, stream,
                     (const f32x4*)x, (const f32x4*)h0,
                     (half4*)xh, (half4*)h16, (half4*)(h16 + B_ * D_));
  hipLaunchKernelGGL(gemm_xproj, dim3(6144), dim3(256), 0, stream,
                     xh, WkT, xproj);

  void* kargs[6] = {(void*)&WrT, (void*)&xproj, (void*)&c0,
                    (void*)&out, (void*)&h16, (void*)&bar};
  hipLaunchCooperativeKernel((void*)lstm_scan, dim3(64), dim3(512), kargs, 0, stream);
}